// Round 1
// baseline (771.941 us; speedup 1.0000x reference)
//
#include <hip/hip_runtime.h>

#define TSTEPS 500
#define BB 32
#define N0 512
#define N1 1024
#define N2 512

// ---------------- GLIFR neuron update (matches reference arithmetic) -------
__device__ __forceinline__ void neuron_update(float& v, float& a0, float& a1,
                                              float x, float& s_out) {
    const float DT = 0.05f;
    const float R = 1.0f / 9.43f;
    const float I0c = 700.0f;
    const float K_M = 1.0f / (R * I0c * DT);
    const float THRESH = 10.0f, SPIKE_R = 20.0f, INV_SIGMA = 0.1f;
    const float AMP0 = -9.18f, AMP1 = -198.94f;
    const float K0 = 0.003f, K1 = 0.1f;

    float syn = I0c * x;
    float itot = syn + a0 + a1;
    // spike rate from PRE-update v
    float s = SPIKE_R / (1.0f + __expf(-(v - THRESH) * INV_SIGMA));
    float s_dt = s * DT;
    float na0 = a0 * (1.0f - DT * K0) + s_dt * (a0 + AMP0);
    float na1 = a1 * (1.0f - DT * K1) + s_dt * (a1 + AMP1);
    float nv = v + DT * K_M * (R * itot - v) + s_dt * (0.0f - v);
    a0 = na0; a1 = na1; v = nv;
    s_out = s;
}

// ---------------- per-layer sequential scan (parallel over neurons) --------
// FIRST_LAYER: drive = raw input at t. Otherwise drive = proj[t-1] (0 at t=0).
template <int NWIDTH, bool FIRST_LAYER>
__global__ void scan_kernel(const float* __restrict__ drive,
                            float* __restrict__ sout) {
    const int idx = blockIdx.x * blockDim.x + threadIdx.x;
    const int stride = BB * NWIDTH;
    float v = 0.f, a0 = 0.f, a1 = 0.f;
#pragma unroll 2
    for (int t = 0; t < TSTEPS; ++t) {
        float x;
        if (FIRST_LAYER) {
            x = drive[t * stride + idx];
        } else {
            x = (t == 0) ? 0.0f : drive[(t - 1) * stride + idx];
        }
        float s;
        neuron_update(v, a0, a1, x, s);
        sout[t * stride + idx] = s;
    }
}

// ---------------- fp32 tiled GEMM: C[M,N] = A[M,K] * Bm[N,K]^T -------------
#define BM 128
#define BN 128
#define BK 16
#define PADL 4

__global__ __launch_bounds__(256, 2) void gemm_tn(const float* __restrict__ A,
                                                  const float* __restrict__ Bm,
                                                  float* __restrict__ C,
                                                  int M, int N, int K) {
    __shared__ float As[BK][BM + PADL];
    __shared__ float Bs[BK][BN + PADL];
    const int m0 = blockIdx.x * BM;
    const int n0 = blockIdx.y * BN;
    const int tid = threadIdx.x;
    const int tm = tid >> 4;   // 0..15
    const int tn = tid & 15;   // 0..15

    float acc[8][8];
#pragma unroll
    for (int i = 0; i < 8; i++)
#pragma unroll
        for (int j = 0; j < 8; j++) acc[i][j] = 0.f;

    const int lrow = tid >> 2;  // 0..63
    const int lc4 = tid & 3;    // 0..3

    for (int k0 = 0; k0 < K; k0 += BK) {
#pragma unroll
        for (int h = 0; h < 2; ++h) {
            const int r = lrow + h * 64;
            const float4 av = *reinterpret_cast<const float4*>(
                &A[(size_t)(m0 + r) * K + k0 + lc4 * 4]);
            As[lc4 * 4 + 0][r] = av.x;
            As[lc4 * 4 + 1][r] = av.y;
            As[lc4 * 4 + 2][r] = av.z;
            As[lc4 * 4 + 3][r] = av.w;
            const float4 bv = *reinterpret_cast<const float4*>(
                &Bm[(size_t)(n0 + r) * K + k0 + lc4 * 4]);
            Bs[lc4 * 4 + 0][r] = bv.x;
            Bs[lc4 * 4 + 1][r] = bv.y;
            Bs[lc4 * 4 + 2][r] = bv.z;
            Bs[lc4 * 4 + 3][r] = bv.w;
        }
        __syncthreads();
#pragma unroll
        for (int kk = 0; kk < BK; ++kk) {
            const float4 a0v = *reinterpret_cast<const float4*>(&As[kk][tm * 8]);
            const float4 a1v = *reinterpret_cast<const float4*>(&As[kk][tm * 8 + 4]);
            const float4 b0v = *reinterpret_cast<const float4*>(&Bs[kk][tn * 8]);
            const float4 b1v = *reinterpret_cast<const float4*>(&Bs[kk][tn * 8 + 4]);
            const float a[8] = {a0v.x, a0v.y, a0v.z, a0v.w,
                                a1v.x, a1v.y, a1v.z, a1v.w};
            const float b[8] = {b0v.x, b0v.y, b0v.z, b0v.w,
                                b1v.x, b1v.y, b1v.z, b1v.w};
#pragma unroll
            for (int i = 0; i < 8; i++)
#pragma unroll
                for (int j = 0; j < 8; j++) acc[i][j] += a[i] * b[j];
        }
        __syncthreads();
    }

#pragma unroll
    for (int i = 0; i < 8; i++) {
        const int r = m0 + tm * 8 + i;
        float4 c0 = {acc[i][0], acc[i][1], acc[i][2], acc[i][3]};
        float4 c1 = {acc[i][4], acc[i][5], acc[i][6], acc[i][7]};
        *reinterpret_cast<float4*>(&C[(size_t)r * N + n0 + tn * 8]) = c0;
        *reinterpret_cast<float4*>(&C[(size_t)r * N + n0 + tn * 8 + 4]) = c1;
    }
}

extern "C" void kernel_launch(void* const* d_in, const int* in_sizes, int n_in,
                              void* d_out, int out_size, void* d_ws,
                              size_t ws_size, hipStream_t stream) {
    const float* inputs = (const float*)d_in[0];  // [500,32,512]
    const float* W1 = (const float*)d_in[1];      // [1024,512]
    const float* W2 = (const float*)d_in[2];      // [512,1024]
    float* out = (float*)d_out;                   // [500,32,512]
    float* ws = (float*)d_ws;

    // workspace layout (floats):
    //   s0  : 500*32*512  = 8,192,000   (reused as x2m after gemm1)
    //   x1m : 500*32*1024 = 16,384,000
    //   s1  : 500*32*1024 = 16,384,000
    float* s0 = ws;
    float* x2m = ws;  // alias: s0 dead after gemm1
    float* x1m = ws + 8192000;
    float* s1 = ws + 8192000 + 16384000;

    const int MROWS = TSTEPS * BB;  // 16000

    // 1) layer-0 recurrence, all timesteps
    scan_kernel<N0, true><<<(BB * N0) / 256, 256, 0, stream>>>(inputs, s0);
    // 2) X1 = S0 @ W1^T   [16000,512] x [1024,512]^T -> [16000,1024]
    gemm_tn<<<dim3(MROWS / BM, N1 / BN), 256, 0, stream>>>(s0, W1, x1m, MROWS,
                                                           N1, N0);
    // 3) layer-1 recurrence (drive delayed by 1 step)
    scan_kernel<N1, false><<<(BB * N1) / 256, 256, 0, stream>>>(x1m, s1);
    // 4) X2 = S1 @ W2^T   [16000,1024] x [512,1024]^T -> [16000,512]
    gemm_tn<<<dim3(MROWS / BM, N2 / BN), 256, 0, stream>>>(s1, W2, x2m, MROWS,
                                                           N2, N1);
    // 5) layer-2 recurrence -> output spikes
    scan_kernel<N2, false><<<(BB * N2) / 256, 256, 0, stream>>>(x2m, out);
}

// Round 2
// 321.228 us; speedup vs baseline: 2.4031x; 2.4031x over previous
//
#include <hip/hip_runtime.h>
#include <stdint.h>

#define TSTEPS 500
#define BB 32
#define N0 512
#define N1 1024
#define N2 512

typedef unsigned short ushort_t;
typedef __attribute__((ext_vector_type(8))) short short8;
typedef __attribute__((ext_vector_type(4))) float f32x4;

// ---------------- bf16 helpers (manual, RNE) ------------------------------
__device__ __forceinline__ ushort_t f2b(float x) {
    union { float f; uint32_t u; } c; c.f = x;
    uint32_t r = (c.u + 0x7fffu + ((c.u >> 16) & 1u)) >> 16;
    return (ushort_t)r;
}
__device__ __forceinline__ float b2f(ushort_t u) {
    union { uint32_t u; float f; } c; c.u = ((uint32_t)u) << 16;
    return c.f;
}

// ---------------- GLIFR neuron update (identical arithmetic to round 1) ----
__device__ __forceinline__ void neuron_update(float& v, float& a0, float& a1,
                                              float x, float& s_out) {
    const float DT = 0.05f;
    const float R = 1.0f / 9.43f;
    const float I0c = 700.0f;
    const float K_M = 1.0f / (R * I0c * DT);
    const float THRESH = 10.0f, SPIKE_R = 20.0f, INV_SIGMA = 0.1f;
    const float AMP0 = -9.18f, AMP1 = -198.94f;
    const float K0 = 0.003f, K1 = 0.1f;

    float syn = I0c * x;
    float itot = syn + a0 + a1;
    float s = SPIKE_R / (1.0f + __expf(-(v - THRESH) * INV_SIGMA));
    float s_dt = s * DT;
    float na0 = a0 * (1.0f - DT * K0) + s_dt * (a0 + AMP0);
    float na1 = a1 * (1.0f - DT * K1) + s_dt * (a1 + AMP1);
    float nv = v + DT * K_M * (R * itot - v) + s_dt * (0.0f - v);
    a0 = na0; a1 = na1; v = nv;
    s_out = s;
}

// ---------------- per-layer scan, 4-deep software-pipelined loads ----------
// MODE 0: fp32 drive at t (first layer), split bf16 hi/lo spike output
// MODE 1: split drive at t-1, split spike output (x/s may alias, shifted)
// MODE 2: split drive at t-1, fp32 spike output (final layer)
template <int NW, int MODE>
__global__ void scan_kernel(const float* fin, const ushort_t* xh,
                            const ushort_t* xl, ushort_t* sh, ushort_t* sl,
                            float* fout) {
    const int idx = blockIdx.x * blockDim.x + threadIdx.x;
    const int S = BB * NW;

    auto LD = [&](int t) -> float {
        if (MODE == 0) {
            return fin[(size_t)t * S + idx];
        } else {
            // drive at step t uses projection of step t-1 (t>=1 guaranteed)
            size_t o = (size_t)(t - 1) * S + idx;
            return b2f(xh[o]) + b2f(xl[o]);
        }
    };

    float v = 0.f, a0 = 0.f, a1 = 0.f;

    auto STEP = [&](int t, float x) {
        float s;
        neuron_update(v, a0, a1, x, s);
        size_t o = (size_t)t * S + idx;
        if (MODE == 2) {
            fout[o] = s;
        } else {
            ushort_t hi = f2b(s);
            sh[o] = hi;
            sl[o] = f2b(s - b2f(hi));
        }
    };

    // 4-deep prefetch pipeline: loads always precede the store that may
    // overwrite an earlier (already-consumed) slot, so aliasing is safe.
    float p0 = (MODE == 0) ? LD(0) : 0.f;
    float p1 = LD(1), p2 = LD(2), p3 = LD(3);

    for (int t = 0; t < TSTEPS - 4; t += 4) {
        float q0 = LD(t + 4), q1 = LD(t + 5), q2 = LD(t + 6), q3 = LD(t + 7);
        STEP(t, p0); STEP(t + 1, p1); STEP(t + 2, p2); STEP(t + 3, p3);
        p0 = q0; p1 = q1; p2 = q2; p3 = q3;
    }
    STEP(TSTEPS - 4, p0); STEP(TSTEPS - 3, p1);
    STEP(TSTEPS - 2, p2); STEP(TSTEPS - 1, p3);
}

// ---------------- weight split: fp32 -> bf16 hi/lo planes ------------------
__global__ void wsplit(const float* __restrict__ W1, const float* __restrict__ W2,
                       ushort_t* __restrict__ w1h, ushort_t* __restrict__ w1l,
                       ushort_t* __restrict__ w2h, ushort_t* __restrict__ w2l) {
    int i = blockIdx.x * 256 + threadIdx.x;  // 0..524287
    float a = W1[i];
    ushort_t h = f2b(a);
    w1h[i] = h; w1l[i] = f2b(a - b2f(h));
    float b = W2[i];
    h = f2b(b);
    w2h[i] = h; w2l[i] = f2b(b - b2f(h));
}

// ---------------- bf16x3-split MFMA GEMM -----------------------------------
// C[M,N] = A[M,K] * B[N,K]^T with A ~ Ah+Al, B ~ Bh+Bl (bf16 planes).
// Output written as bf16 hi/lo planes. 128x128 tile, BK=32, m97 structure.
__global__ __launch_bounds__(256, 2) void gemm_bf16x3(
    const ushort_t* Ah, const ushort_t* Al,
    const ushort_t* Bh, const ushort_t* Bl,
    ushort_t* Ch, ushort_t* Cl, int Ncols, int K) {
    __shared__ char lds[32768];  // 4 planes x [128 rows][32 k] bf16 (8KB each)
    const int tid = threadIdx.x;
    const int lane = tid & 63, wave = tid >> 6;
    const int m0 = blockIdx.x * 128, n0 = blockIdx.y * 128;

    // wave w stages plane w: 0=Ah 1=Al 2=Bh 3=Bl
    const ushort_t* gbase;
    int trow0;
    if (wave == 0)      { gbase = Ah; trow0 = m0; }
    else if (wave == 1) { gbase = Al; trow0 = m0; }
    else if (wave == 2) { gbase = Bh; trow0 = n0; }
    else                { gbase = Bl; trow0 = n0; }
    const size_t rowb = (size_t)K * 2;  // row stride in bytes
    // lane's linear slice: row = i*16 + (lane>>2), 16B chunk (lane&3)
    const char* gsrc = (const char*)gbase +
                       (size_t)(trow0 + (lane >> 2)) * rowb + (size_t)(lane & 3) * 16;

    const int KSTEPS = K / 32;
    f32x4 acc[4][4];
#pragma unroll
    for (int i = 0; i < 4; ++i)
#pragma unroll
        for (int j = 0; j < 4; ++j) acc[i][j] = (f32x4){0.f, 0.f, 0.f, 0.f};

    const int wm = wave >> 1, wn = wave & 1;
    const int r4 = lane & 15, kg = lane >> 4;
    // fragment byte offset within a plane (linear [row][k] layout, m97 pattern)
    const int fA = (wm * 64 + r4) * 64 + kg * 16;
    const int fB = (wn * 64 + r4) * 64 + kg * 16;

    for (int ks = 0; ks < KSTEPS; ++ks) {
        // ---- stage this K-tile: 8 x global_load_lds(16B) per wave ----
#pragma unroll
        for (int i = 0; i < 8; ++i) {
            __builtin_amdgcn_global_load_lds(
                (const __attribute__((address_space(1))) uint32_t*)(
                    gsrc + (size_t)i * 16 * rowb + (size_t)ks * 64),
                (__attribute__((address_space(3))) uint32_t*)(
                    lds + wave * 8192 + i * 1024),
                16, 0, 0);
        }
        __syncthreads();  // drains vmcnt + barrier

        short8 ah[4], al[4], bh[4], bl[4];
#pragma unroll
        for (int i = 0; i < 4; ++i) {
            ah[i] = *(const short8*)(lds + 0     + fA + i * 1024);
            al[i] = *(const short8*)(lds + 8192  + fA + i * 1024);
            bh[i] = *(const short8*)(lds + 16384 + fB + i * 1024);
            bl[i] = *(const short8*)(lds + 24576 + fB + i * 1024);
        }
#pragma unroll
        for (int i = 0; i < 4; ++i)
#pragma unroll
            for (int j = 0; j < 4; ++j) {
                acc[i][j] = __builtin_amdgcn_mfma_f32_16x16x32_bf16(
                    ah[i], bh[j], acc[i][j], 0, 0, 0);
                acc[i][j] = __builtin_amdgcn_mfma_f32_16x16x32_bf16(
                    ah[i], bl[j], acc[i][j], 0, 0, 0);
                acc[i][j] = __builtin_amdgcn_mfma_f32_16x16x32_bf16(
                    al[i], bh[j], acc[i][j], 0, 0, 0);
            }
        __syncthreads();
    }

    // ---- epilogue: C/D layout col=lane&15, row=(lane>>4)*4+reg ----
    const int row_l = kg * 4;
#pragma unroll
    for (int i = 0; i < 4; ++i)
#pragma unroll
        for (int j = 0; j < 4; ++j)
#pragma unroll
            for (int r = 0; r < 4; ++r) {
                int row = m0 + wm * 64 + i * 16 + row_l + r;
                int col = n0 + wn * 64 + j * 16 + r4;
                float val = acc[i][j][r];
                ushort_t hi = f2b(val);
                size_t o = (size_t)row * Ncols + col;
                Ch[o] = hi;
                Cl[o] = f2b(val - b2f(hi));
            }
}

extern "C" void kernel_launch(void* const* d_in, const int* in_sizes, int n_in,
                              void* d_out, int out_size, void* d_ws,
                              size_t ws_size, hipStream_t stream) {
    const float* inputs = (const float*)d_in[0];  // [500,32,512]
    const float* W1 = (const float*)d_in[1];      // [1024,512]
    const float* W2 = (const float*)d_in[2];      // [512,1024]
    float* out = (float*)d_out;                   // [500,32,512]
    char* ws = (char*)d_ws;

    // workspace layout (bytes):
    //   s0h : 16,384,000   [16000,512] bf16      (aliased later as x2h)
    //   s0l : 16,384,000                         (aliased later as x2l)
    //   r1h : 32,833,536   [501*32,1024] bf16    (x1 rows 1..500, s1 rows 0..499)
    //   r1l : 32,833,536
    //   w1h/w1l/w2h/w2l : 1,048,576 each
    ushort_t* s0h = (ushort_t*)(ws);
    ushort_t* s0l = (ushort_t*)(ws + 16384000);
    ushort_t* r1h = (ushort_t*)(ws + 32768000);
    ushort_t* r1l = (ushort_t*)(ws + 32768000 + 32833536);
    ushort_t* w1h = (ushort_t*)(ws + 98435072);
    ushort_t* w1l = (ushort_t*)(ws + 99483648);
    ushort_t* w2h = (ushort_t*)(ws + 100532224);
    ushort_t* w2l = (ushort_t*)(ws + 101580800);

    ushort_t* x1h = r1h + 32 * 1024;  // +1 timestep: x1[t] lives at region row t+1
    ushort_t* x1l = r1l + 32 * 1024;
    ushort_t* x2h = s0h;              // s0 dead after gemm1
    ushort_t* x2l = s0l;

    // 1) split weights into bf16 hi/lo planes
    wsplit<<<2048, 256, 0, stream>>>(W1, W2, w1h, w1l, w2h, w2l);
    // 2) layer-0 recurrence (fp32 input drive) -> split spikes
    scan_kernel<N0, 0><<<256, 64, 0, stream>>>(inputs, nullptr, nullptr,
                                               s0h, s0l, nullptr);
    // 3) X1 = S0 @ W1^T  [16000,512] x [1024,512]^T -> split [16000,1024]
    gemm_bf16x3<<<dim3(125, 8), 256, 0, stream>>>(s0h, s0l, w1h, w1l,
                                                  x1h, x1l, N1, N0);
    // 4) layer-1 recurrence; s1 overwrites x1 shifted one step (safe in-place)
    scan_kernel<N1, 1><<<512, 64, 0, stream>>>(nullptr, x1h, x1l,
                                               r1h, r1l, nullptr);
    // 5) X2 = S1 @ W2^T  [16000,1024] x [512,1024]^T -> split [16000,512]
    gemm_bf16x3<<<dim3(125, 4), 256, 0, stream>>>(r1h, r1l, w2h, w2l,
                                                  x2h, x2l, N2, N1);
    // 6) layer-2 recurrence -> fp32 output spikes
    scan_kernel<N2, 2><<<256, 64, 0, stream>>>(nullptr, x2h, x2l,
                                               nullptr, nullptr, out);
}

// Round 3
// 258.559 us; speedup vs baseline: 2.9855x; 1.2424x over previous
//
#include <hip/hip_runtime.h>
#include <stdint.h>

#define TSTEPS 500
#define BB 32
#define N0 512
#define N1 1024
#define N2 512

typedef unsigned short ushort_t;
typedef __attribute__((ext_vector_type(8))) short short8;
typedef __attribute__((ext_vector_type(4))) float f32x4;

// ---------------- bf16 helpers (manual, RNE) ------------------------------
__device__ __forceinline__ ushort_t f2b(float x) {
    union { float f; uint32_t u; } c; c.f = x;
    uint32_t r = (c.u + 0x7fffu + ((c.u >> 16) & 1u)) >> 16;
    return (ushort_t)r;
}
__device__ __forceinline__ float b2f(ushort_t u) {
    union { uint32_t u; float f; } c; c.u = ((uint32_t)u) << 16;
    return c.f;
}

// ---------------- GLIFR neuron update -------------------------------------
__device__ __forceinline__ void neuron_update(float& v, float& a0, float& a1,
                                              float x, float& s_out) {
    const float DT = 0.05f;
    const float R = 1.0f / 9.43f;
    const float I0c = 700.0f;
    const float K_M = 1.0f / (R * I0c * DT);
    const float THRESH = 10.0f, SPIKE_R = 20.0f, INV_SIGMA = 0.1f;
    const float AMP0 = -9.18f, AMP1 = -198.94f;
    const float K0 = 0.003f, K1 = 0.1f;

    float syn = I0c * x;
    float itot = syn + a0 + a1;
    float s = SPIKE_R / (1.0f + __expf(-(v - THRESH) * INV_SIGMA));
    float s_dt = s * DT;
    float na0 = a0 * (1.0f - DT * K0) + s_dt * (a0 + AMP0);
    float na1 = a1 * (1.0f - DT * K1) + s_dt * (a1 + AMP1);
    float nv = v + DT * K_M * (R * itot - v) + s_dt * (0.0f - v);
    a0 = na0; a1 = na1; v = nv;
    s_out = s;
}

// ---------------- per-layer scan, 20-deep load pipeline (500 = 25*20) -----
// MODE 0: fp32 drive at t (layer 0), split bf16 spike output
// MODE 1: fp32 drive at t-1,          split bf16 spike output
// MODE 2: fp32 drive at t-1,          fp32 spike output (final layer)
#define PD 20
template <int NW, int MODE>
__global__ void scan_kernel(const float* __restrict__ drive,
                            ushort_t* __restrict__ sh,
                            ushort_t* __restrict__ sl,
                            float* __restrict__ fout) {
    const int idx = blockIdx.x * blockDim.x + threadIdx.x;
    const int S = BB * NW;

    auto LD = [&](int t) -> float {
        if (MODE == 0) return drive[(size_t)t * S + idx];
        return (t == 0) ? 0.0f : drive[(size_t)(t - 1) * S + idx];
    };

    float v = 0.f, a0 = 0.f, a1 = 0.f;

    auto STEP = [&](int t, float x) {
        float s;
        neuron_update(v, a0, a1, x, s);
        size_t o = (size_t)t * S + idx;
        if (MODE == 2) {
            fout[o] = s;
        } else {
            ushort_t hi = f2b(s);
            sh[o] = hi;
            sl[o] = f2b(s - b2f(hi));
        }
    };

    float p[PD];
#pragma unroll
    for (int i = 0; i < PD; ++i) p[i] = LD(i);

    for (int t = 0; t < TSTEPS - PD; t += PD) {  // t = 0..480-PD, steps 0..479
        float q[PD];
#pragma unroll
        for (int i = 0; i < PD; ++i) q[i] = LD(t + PD + i);  // max = 499
#pragma unroll
        for (int i = 0; i < PD; ++i) STEP(t + i, p[i]);
#pragma unroll
        for (int i = 0; i < PD; ++i) p[i] = q[i];
    }
#pragma unroll
    for (int i = 0; i < PD; ++i) STEP(TSTEPS - PD + i, p[i]);
}

// ---------------- weight split: fp32 -> bf16 hi/lo planes ------------------
__global__ void wsplit(const float* __restrict__ W1, const float* __restrict__ W2,
                       ushort_t* __restrict__ w1h, ushort_t* __restrict__ w1l,
                       ushort_t* __restrict__ w2h, ushort_t* __restrict__ w2l) {
    int i = blockIdx.x * 256 + threadIdx.x;  // 0..524287
    float a = W1[i];
    ushort_t h = f2b(a);
    w1h[i] = h; w1l[i] = f2b(a - b2f(h));
    float b = W2[i];
    h = f2b(b);
    w2h[i] = h; w2l[i] = f2b(b - b2f(h));
}

// ---------------- bf16x3-split MFMA GEMM, f32 output -----------------------
// C[M,N] = A[M,K]*B[N,K]^T, A~Ah+Al, B~Bh+Bl. 128x128 tile, BK=32.
// Linear grid + bijective XCD swizzle (NBY = N/128 tiles along N).
// LDS: linear dest, XOR-swizzled global source + XOR-swizzled ds_read.
template <int NBY>
__global__ __launch_bounds__(256, 2) void gemm_bf16x3(
    const ushort_t* Ah, const ushort_t* Al,
    const ushort_t* Bh, const ushort_t* Bl,
    float* C, int Ncols, int K) {
    __shared__ char lds[32768];  // 4 planes x [128 rows][64B] (8KB each)
    const int tid = threadIdx.x;
    const int lane = tid & 63, wave = tid >> 6;

    // bijective XCD swizzle (m204): same-XCD blocks get contiguous wg ids,
    // wg-major ordering is bx-major so each XCD owns a contiguous bx range.
    const int id = blockIdx.x, nwg = gridDim.x;
    const int qq = nwg >> 3, rr = nwg & 7;
    const int xcd = id & 7, jj = id >> 3;
    const int wg = (xcd < rr ? xcd * (qq + 1) : rr * (qq + 1) + (xcd - rr) * qq) + jj;
    const int m0 = (wg / NBY) * 128;
    const int n0 = (wg % NBY) * 128;

    // wave w stages plane w: 0=Ah 1=Al 2=Bh 3=Bl
    const ushort_t* gbase;
    int trow0;
    if (wave == 0)      { gbase = Ah; trow0 = m0; }
    else if (wave == 1) { gbase = Al; trow0 = m0; }
    else if (wave == 2) { gbase = Bh; trow0 = n0; }
    else                { gbase = Bl; trow0 = n0; }
    const size_t rowb = (size_t)K * 2;  // row stride bytes
    // pre-swizzled source chunk: LDS slot (lane&3) of row (lane>>2)+16i must
    // hold global chunk (lane&3)^((row>>1)&3); (row>>1)&3 == (lane>>3)&3 for
    // all i (16-row stride). So each lane reads chunk (lane&3)^((lane>>3)&3).
    const int chunk_sw = (lane & 3) ^ ((lane >> 3) & 3);
    const char* gsrc = (const char*)gbase +
                       (size_t)(trow0 + (lane >> 2)) * rowb + (size_t)chunk_sw * 16;

    const int KSTEPS = K / 32;
    f32x4 acc[4][4];
#pragma unroll
    for (int i = 0; i < 4; ++i)
#pragma unroll
        for (int j = 0; j < 4; ++j) acc[i][j] = (f32x4){0.f, 0.f, 0.f, 0.f};

    const int wm = wave >> 1, wn = wave & 1;
    const int r4 = lane & 15, kg = lane >> 4;
    // XOR-swizzled fragment offset: slot = kg ^ ((r4>>1)&3), same for all i
    const int slot = kg ^ ((r4 >> 1) & 3);
    const int fA = (wm * 64 + r4) * 64 + slot * 16;
    const int fB = (wn * 64 + r4) * 64 + slot * 16;

    for (int ks = 0; ks < KSTEPS; ++ks) {
#pragma unroll
        for (int i = 0; i < 8; ++i) {
            __builtin_amdgcn_global_load_lds(
                (const __attribute__((address_space(1))) uint32_t*)(
                    gsrc + (size_t)i * 16 * rowb + (size_t)ks * 64),
                (__attribute__((address_space(3))) uint32_t*)(
                    lds + wave * 8192 + i * 1024),
                16, 0, 0);
        }
        __syncthreads();

        short8 ah[4], al[4], bh[4], bl[4];
#pragma unroll
        for (int i = 0; i < 4; ++i) {
            ah[i] = *(const short8*)(lds + 0     + fA + i * 1024);
            al[i] = *(const short8*)(lds + 8192  + fA + i * 1024);
            bh[i] = *(const short8*)(lds + 16384 + fB + i * 1024);
            bl[i] = *(const short8*)(lds + 24576 + fB + i * 1024);
        }
#pragma unroll
        for (int i = 0; i < 4; ++i)
#pragma unroll
            for (int j = 0; j < 4; ++j) {
                acc[i][j] = __builtin_amdgcn_mfma_f32_16x16x32_bf16(
                    ah[i], bh[j], acc[i][j], 0, 0, 0);
                acc[i][j] = __builtin_amdgcn_mfma_f32_16x16x32_bf16(
                    ah[i], bl[j], acc[i][j], 0, 0, 0);
                acc[i][j] = __builtin_amdgcn_mfma_f32_16x16x32_bf16(
                    al[i], bh[j], acc[i][j], 0, 0, 0);
            }
        __syncthreads();
    }

    // epilogue: C/D layout col=lane&15, row=(lane>>4)*4+reg; f32 stores
#pragma unroll
    for (int i = 0; i < 4; ++i)
#pragma unroll
        for (int j = 0; j < 4; ++j)
#pragma unroll
            for (int r = 0; r < 4; ++r) {
                int row = m0 + wm * 64 + i * 16 + kg * 4 + r;
                int col = n0 + wn * 64 + j * 16 + r4;
                C[(size_t)row * Ncols + col] = acc[i][j][r];
            }
}

extern "C" void kernel_launch(void* const* d_in, const int* in_sizes, int n_in,
                              void* d_out, int out_size, void* d_ws,
                              size_t ws_size, hipStream_t stream) {
    const float* inputs = (const float*)d_in[0];  // [500,32,512]
    const float* W1 = (const float*)d_in[1];      // [1024,512]
    const float* W2 = (const float*)d_in[2];      // [512,1024]
    float* out = (float*)d_out;                   // [500,32,512]
    char* ws = (char*)d_ws;

    // workspace (bytes):
    //  region A [0, 32,768,000):  s0h(16.38MB)+s0l(16.38MB); later s1h(32.77MB)
    //  region B [32,768,000, 98,304,000): x1 f32 (65.54MB); later x2 f32
    //  region C [98,304,000, 131,072,000): s1l (32.77MB)
    //  weights  [131,072,000, 135,266,304): w1h w1l w2h w2l (1MB each)
    ushort_t* s0h = (ushort_t*)(ws);
    ushort_t* s0l = (ushort_t*)(ws + 16384000);
    ushort_t* s1h = (ushort_t*)(ws);              // s0 dead after gemm1
    float*    x1  = (float*)(ws + 32768000);
    float*    x2  = (float*)(ws + 32768000);      // x1 dead after scan1
    ushort_t* s1l = (ushort_t*)(ws + 98304000);
    ushort_t* w1h = (ushort_t*)(ws + 131072000);
    ushort_t* w1l = (ushort_t*)(ws + 132120576);
    ushort_t* w2h = (ushort_t*)(ws + 133169152);
    ushort_t* w2l = (ushort_t*)(ws + 134217728);

    // 1) split weights
    wsplit<<<2048, 256, 0, stream>>>(W1, W2, w1h, w1l, w2h, w2l);
    // 2) layer-0 recurrence (fp32 input) -> split spikes
    scan_kernel<N0, 0><<<256, 64, 0, stream>>>(inputs, s0h, s0l, nullptr);
    // 3) X1 = S0 @ W1^T -> f32 [16000,1024]; grid 125x8 linear, NBY=8
    gemm_bf16x3<8><<<1000, 256, 0, stream>>>(s0h, s0l, w1h, w1l, x1, N1, N0);
    // 4) layer-1 recurrence -> split spikes (s1h overwrites dead s0 region)
    scan_kernel<N1, 1><<<512, 64, 0, stream>>>(x1, s1h, s1l, nullptr);
    // 5) X2 = S1 @ W2^T -> f32 [16000,512]; grid 125x4 linear, NBY=4
    gemm_bf16x3<4><<<500, 256, 0, stream>>>(s1h, s1l, w2h, w2l, x2, N2, N1);
    // 6) layer-2 recurrence -> fp32 output spikes
    scan_kernel<N2, 2><<<256, 64, 0, stream>>>(x2, nullptr, nullptr, out);
}

// Round 4
// 219.493 us; speedup vs baseline: 3.5169x; 1.1780x over previous
//
#include <hip/hip_runtime.h>
#include <hip/hip_bf16.h>
#include <stdint.h>

#define TSTEPS 500
#define BB 32
#define N0 512
#define N1 1024
#define N2 512

typedef unsigned short ushort_t;
typedef __attribute__((ext_vector_type(8))) short short8;
typedef __attribute__((ext_vector_type(4))) float f32x4;

// ---------------- bf16 helpers --------------------------------------------
__device__ __forceinline__ ushort_t f2b(float x) {
    union { float f; uint32_t u; } c; c.f = x;
    uint32_t r = (c.u + 0x7fffu + ((c.u >> 16) & 1u)) >> 16;
    return (ushort_t)r;
}
__device__ __forceinline__ float b2f(ushort_t u) {
    union { uint32_t u; float f; } c; c.u = ((uint32_t)u) << 16;
    return c.f;
}

// ---------------- GLIFR step, algebraically reduced ------------------------
// Returns sigma = sigmoid((v-10)/10) == s_dt (since SPIKE_R*DT == 1).
// Reference spike s = 20*sigma; the 20 is folded into W (and final store).
__device__ __forceinline__ float glifr_step(float& v, float& a0, float& a1,
                                            float x) {
    const float INV_I0 = 1.0f / 700.0f;
    const float C2 = 9.43f / 700.0f;            // DT*K_M = 1/(R*I0)
    const float CE = 0.14426950408889634f;      // 0.1*log2(e)
    const float CE10 = 1.4426950408889634f;     // 1.0*log2(e)
    const float C0 = 1.0f - 0.05f * 0.003f;
    const float C1 = 1.0f - 0.05f * 0.1f;
    const float AMP0 = -9.18f, AMP1 = -198.94f;

    float asum = a0 + a1;
    float drv = fmaf(asum, INV_I0, x);              // itot/I0
    float e = exp2f(fmaf(v, -CE, CE10));            // exp((10-v)*0.1)
    float sig = __builtin_amdgcn_rcpf(1.0f + e);    // sigmoid
    float na0 = fmaf(sig, a0 + AMP0, a0 * C0);
    float na1 = fmaf(sig, a1 + AMP1, a1 * C1);
    float nv = fmaf(-sig, v, fmaf(-C2, v, v + drv));
    a0 = na0; a1 = na1; v = nv;
    return sig;
}

// ---------------- per-layer scan: f32 in, f32 sigma out --------------------
// MODE 0: drive at t. MODE 1: drive at t-1 (0 at t=0). MODE 2: same as 1 but
// output scaled by SPIKE_R=20 (final layer -> d_out).
#define PD 20
template <int NW, int MODE>
__global__ void scan_kernel(const float* __restrict__ drive,
                            float* __restrict__ sout) {
    const int idx = blockIdx.x * blockDim.x + threadIdx.x;
    const int S = BB * NW;

    auto LD = [&](int t) -> float {
        if (MODE == 0) return drive[(size_t)t * S + idx];
        return (t == 0) ? 0.0f : drive[(size_t)(t - 1) * S + idx];
    };

    float v = 0.f, a0 = 0.f, a1 = 0.f;

    auto STEP = [&](int t, float x) {
        float sig = glifr_step(v, a0, a1, x);
        sout[(size_t)t * S + idx] = (MODE == 2) ? 20.0f * sig : sig;
    };

    float p[PD];
#pragma unroll
    for (int i = 0; i < PD; ++i) p[i] = LD(i);

    for (int t = 0; t < TSTEPS - PD; t += PD) {
        float q[PD];
#pragma unroll
        for (int i = 0; i < PD; ++i) q[i] = LD(t + PD + i);
#pragma unroll
        for (int i = 0; i < PD; ++i) STEP(t + i, p[i]);
#pragma unroll
        for (int i = 0; i < PD; ++i) p[i] = q[i];
    }
#pragma unroll
    for (int i = 0; i < PD; ++i) STEP(TSTEPS - PD + i, p[i]);
}

// ---------------- weight split: fp32 -> bf16 hi/lo planes, scaled by 20 ----
__global__ void wsplit(const float* __restrict__ W1, const float* __restrict__ W2,
                       ushort_t* __restrict__ w1h, ushort_t* __restrict__ w1l,
                       ushort_t* __restrict__ w2h, ushort_t* __restrict__ w2l) {
    int i = blockIdx.x * 256 + threadIdx.x;  // 0..524287
    float a = 20.0f * W1[i];
    ushort_t h = f2b(a);
    w1h[i] = h; w1l[i] = f2b(a - b2f(h));
    float b = 20.0f * W2[i];
    h = f2b(b);
    w2h[i] = h; w2l[i] = f2b(b - b2f(h));
}

// ---------------- bf16x3-split MFMA GEMM, f32 A (split in-kernel) ----------
// C[M,N] = A[M,K]*B[N,K]^T; A f32 split to hi/lo bf16 during LDS staging;
// B pre-split planes via global_load_lds (waves 2,3). 128x128 tile, BK=32.
template <int NBY>
__global__ __launch_bounds__(256, 2) void gemm_x3(
    const float* __restrict__ A,
    const ushort_t* __restrict__ Bh, const ushort_t* __restrict__ Bl,
    float* __restrict__ C, int Ncols, int K) {
    __shared__ char lds[32768];  // Ah | Al | Bh | Bl, 8KB each
    const int tid = threadIdx.x;
    const int lane = tid & 63, wave = tid >> 6;

    // bijective XCD swizzle (m204)
    const int id = blockIdx.x, nwg = gridDim.x;
    const int qq = nwg >> 3, rr = nwg & 7;
    const int xcd = id & 7, jj = id >> 3;
    const int wg = (xcd < rr ? xcd * (qq + 1) : rr * (qq + 1) + (xcd - rr) * qq) + jj;
    const int m0 = (wg / NBY) * 128;
    const int n0 = (wg % NBY) * 128;

    // B staging (waves 2,3): pre-swizzled global source, linear LDS dest
    const ushort_t* gB = (wave == 2) ? Bh : Bl;
    const int chunk_sw = (lane & 3) ^ ((lane >> 3) & 3);
    const size_t rowbB = (size_t)K * 2;
    const char* gsrcB = (const char*)gB +
                        (size_t)(n0 + (lane >> 2)) * rowbB + (size_t)chunk_sw * 16;

    // A staging (all 256 threads): 4 float4 per K-tile, swizzled ds_write
    const int r0 = tid >> 3, c4 = tid & 7;          // row base 0..31, chunk 0..7
    const int ch = (c4 >> 1) ^ ((r0 >> 1) & 3);     // swizzled 16B slot
    const int aoff = r0 * 64 + ch * 16 + (c4 & 1) * 8;
    const float* aSrc = A + (size_t)(m0 + r0) * K + c4 * 4;

    const int KSTEPS = K / 32;
    f32x4 acc[4][4];
#pragma unroll
    for (int i = 0; i < 4; ++i)
#pragma unroll
        for (int j = 0; j < 4; ++j) acc[i][j] = (f32x4){0.f, 0.f, 0.f, 0.f};

    const int wm = wave >> 1, wn = wave & 1;
    const int r4 = lane & 15, kg = lane >> 4;
    const int slot = kg ^ ((r4 >> 1) & 3);
    const int fA = (wm * 64 + r4) * 64 + slot * 16;
    const int fB = (wn * 64 + r4) * 64 + slot * 16;

    for (int ks = 0; ks < KSTEPS; ++ks) {
        if (wave >= 2) {
#pragma unroll
            for (int i = 0; i < 8; ++i) {
                __builtin_amdgcn_global_load_lds(
                    (const __attribute__((address_space(1))) uint32_t*)(
                        gsrcB + (size_t)i * 16 * rowbB + (size_t)ks * 64),
                    (__attribute__((address_space(3))) uint32_t*)(
                        lds + 16384 + (wave - 2) * 8192 + i * 1024),
                    16, 0, 0);
            }
        }
#pragma unroll
        for (int i = 0; i < 4; ++i) {
            const float4 av = *reinterpret_cast<const float4*>(
                aSrc + (size_t)i * 32 * K + (size_t)ks * 32);
            __hip_bfloat162 h01 = __float22bfloat162_rn(make_float2(av.x, av.y));
            __hip_bfloat162 h23 = __float22bfloat162_rn(make_float2(av.z, av.w));
            uint32_t hi01 = *reinterpret_cast<uint32_t*>(&h01);
            uint32_t hi23 = *reinterpret_cast<uint32_t*>(&h23);
            float lx = av.x - __uint_as_float(hi01 << 16);
            float ly = av.y - __uint_as_float(hi01 & 0xffff0000u);
            float lz = av.z - __uint_as_float(hi23 << 16);
            float lw = av.w - __uint_as_float(hi23 & 0xffff0000u);
            __hip_bfloat162 l01 = __float22bfloat162_rn(make_float2(lx, ly));
            __hip_bfloat162 l23 = __float22bfloat162_rn(make_float2(lz, lw));
            uint32_t lo01 = *reinterpret_cast<uint32_t*>(&l01);
            uint32_t lo23 = *reinterpret_cast<uint32_t*>(&l23);
            *reinterpret_cast<uint2*>(lds + aoff + i * 2048) =
                make_uint2(hi01, hi23);
            *reinterpret_cast<uint2*>(lds + 8192 + aoff + i * 2048) =
                make_uint2(lo01, lo23);
        }
        __syncthreads();

        short8 ah[4], al[4], bh[4], bl[4];
#pragma unroll
        for (int i = 0; i < 4; ++i) {
            ah[i] = *(const short8*)(lds + 0     + fA + i * 1024);
            al[i] = *(const short8*)(lds + 8192  + fA + i * 1024);
            bh[i] = *(const short8*)(lds + 16384 + fB + i * 1024);
            bl[i] = *(const short8*)(lds + 24576 + fB + i * 1024);
        }
#pragma unroll
        for (int i = 0; i < 4; ++i)
#pragma unroll
            for (int j = 0; j < 4; ++j) {
                acc[i][j] = __builtin_amdgcn_mfma_f32_16x16x32_bf16(
                    ah[i], bh[j], acc[i][j], 0, 0, 0);
                acc[i][j] = __builtin_amdgcn_mfma_f32_16x16x32_bf16(
                    ah[i], bl[j], acc[i][j], 0, 0, 0);
                acc[i][j] = __builtin_amdgcn_mfma_f32_16x16x32_bf16(
                    al[i], bh[j], acc[i][j], 0, 0, 0);
            }
        __syncthreads();
    }

    // epilogue: C/D layout col=lane&15, row=(lane>>4)*4+reg
#pragma unroll
    for (int i = 0; i < 4; ++i)
#pragma unroll
        for (int j = 0; j < 4; ++j)
#pragma unroll
            for (int r = 0; r < 4; ++r) {
                int row = m0 + wm * 64 + i * 16 + kg * 4 + r;
                int col = n0 + wn * 64 + j * 16 + r4;
                C[(size_t)row * Ncols + col] = acc[i][j][r];
            }
}

extern "C" void kernel_launch(void* const* d_in, const int* in_sizes, int n_in,
                              void* d_out, int out_size, void* d_ws,
                              size_t ws_size, hipStream_t stream) {
    const float* inputs = (const float*)d_in[0];  // [500,32,512]
    const float* W1 = (const float*)d_in[1];      // [1024,512]
    const float* W2 = (const float*)d_in[2];      // [512,1024]
    float* out = (float*)d_out;                   // [500,32,512]
    char* ws = (char*)d_ws;

    // workspace (bytes):
    //  region A [0, 65,536,000): s0 f32 (32.77MB); later s1 f32 (65.54MB)
    //  region B [65,536,000, 131,072,000): x1 f32 (65.54MB); later x2 f32
    //  weights  [131,072,000, 135,266,304): w1h w1l w2h w2l (1MB each)
    float* s0 = (float*)ws;
    float* s1 = (float*)ws;                   // s0 dead after gemm1
    float* x1 = (float*)(ws + 65536000);
    float* x2 = (float*)(ws + 65536000);      // x1 dead after scan1
    ushort_t* w1h = (ushort_t*)(ws + 131072000);
    ushort_t* w1l = (ushort_t*)(ws + 132120576);
    ushort_t* w2h = (ushort_t*)(ws + 133169152);
    ushort_t* w2l = (ushort_t*)(ws + 134217728);

    // 1) split weights (scaled by SPIKE_R=20)
    wsplit<<<2048, 256, 0, stream>>>(W1, W2, w1h, w1l, w2h, w2l);
    // 2) layer-0 recurrence -> sigma f32
    scan_kernel<N0, 0><<<256, 64, 0, stream>>>(inputs, s0);
    // 3) X1 = S0 @ (20*W1)^T -> f32 [16000,1024]
    gemm_x3<8><<<1000, 256, 0, stream>>>(s0, w1h, w1l, x1, N1, N0);
    // 4) layer-1 recurrence -> sigma f32
    scan_kernel<N1, 1><<<512, 64, 0, stream>>>(x1, s1);
    // 5) X2 = S1 @ (20*W2)^T -> f32 [16000,512]
    gemm_x3<4><<<500, 256, 0, stream>>>(s1, w2h, w2l, x2, N2, N1);
    // 6) layer-2 recurrence -> spikes (20*sigma) -> out
    scan_kernel<N2, 2><<<256, 64, 0, stream>>>(x2, out);
}

// Round 5
// 211.705 us; speedup vs baseline: 3.6463x; 1.0368x over previous
//
#include <hip/hip_runtime.h>
#include <hip/hip_bf16.h>
#include <stdint.h>

#define TSTEPS 500
#define BB 32
#define N0 512
#define N1 1024
#define N2 512

typedef unsigned short ushort_t;
typedef __attribute__((ext_vector_type(8))) short short8;
typedef __attribute__((ext_vector_type(4))) float f32x4;

// ---------------- bf16 helpers --------------------------------------------
__device__ __forceinline__ ushort_t f2b(float x) {
    union { float f; uint32_t u; } c; c.f = x;
    uint32_t r = (c.u + 0x7fffu + ((c.u >> 16) & 1u)) >> 16;
    return (ushort_t)r;
}
__device__ __forceinline__ float b2f(ushort_t u) {
    union { uint32_t u; float f; } c; c.u = ((uint32_t)u) << 16;
    return c.f;
}

// ---------------- GLIFR step, algebraically reduced ------------------------
// Returns sigma = sigmoid((v-10)/10) == s*DT (SPIKE_R*DT == 1); the 20 is
// folded into the weight planes and the final store.
__device__ __forceinline__ float glifr_step(float& v, float& a0, float& a1,
                                            float x) {
    const float INV_I0 = 1.0f / 700.0f;
    const float C2 = 9.43f / 700.0f;            // DT*K_M = 1/(R*I0)
    const float CE = 0.14426950408889634f;      // 0.1*log2(e)
    const float CE10 = 1.4426950408889634f;     // 1.0*log2(e)
    const float C0 = 1.0f - 0.05f * 0.003f;
    const float C1 = 1.0f - 0.05f * 0.1f;
    const float AMP0 = -9.18f, AMP1 = -198.94f;

    float asum = a0 + a1;
    float drv = fmaf(asum, INV_I0, x);
    float e = exp2f(fmaf(v, -CE, CE10));            // exp((10-v)*0.1)
    float sig = __builtin_amdgcn_rcpf(1.0f + e);    // sigmoid
    float na0 = fmaf(sig, a0 + AMP0, a0 * C0);
    float na1 = fmaf(sig, a1 + AMP1, a1 * C1);
    float nv = fmaf(-sig, v, fmaf(-C2, v, v + drv));
    a0 = na0; a1 = na1; v = nv;
    return sig;
}

// ---------------- scan body: f32 drive in, packed(hi|lo<<16) or f32 out ----
// MODE 0: drive at t.  MODE 1: drive at t-1 (0 at t=0).  MODE 2: drive at
// t-1, f32 out scaled by SPIKE_R=20 (final layer).
#define PD 20
template <int NW, int MODE>
__device__ __forceinline__ void scan_body(const float* __restrict__ drive,
                                          uint32_t* __restrict__ pout,
                                          float* __restrict__ fout, int idx) {
    const int S = BB * NW;

    auto LD = [&](int t) -> float {
        if (MODE == 0) return drive[(size_t)t * S + idx];
        return (t == 0) ? 0.0f : drive[(size_t)(t - 1) * S + idx];
    };

    float v = 0.f, a0 = 0.f, a1 = 0.f;

    auto STEP = [&](int t, float x) {
        float sig = glifr_step(v, a0, a1, x);
        size_t o = (size_t)t * S + idx;
        if (MODE == 2) {
            fout[o] = 20.0f * sig;
        } else {
            ushort_t hi = f2b(sig);
            float lo = sig - b2f(hi);
            pout[o] = (uint32_t)hi | ((uint32_t)f2b(lo) << 16);
        }
    };

    float p[PD];
#pragma unroll
    for (int i = 0; i < PD; ++i) p[i] = LD(i);

    for (int t = 0; t < TSTEPS - PD; t += PD) {
        float q[PD];
#pragma unroll
        for (int i = 0; i < PD; ++i) q[i] = LD(t + PD + i);
#pragma unroll
        for (int i = 0; i < PD; ++i) STEP(t + i, p[i]);
#pragma unroll
        for (int i = 0; i < PD; ++i) p[i] = q[i];
    }
#pragma unroll
    for (int i = 0; i < PD; ++i) STEP(TSTEPS - PD + i, p[i]);
}

// ---------------- scan0 fused with weight split ----------------------------
__global__ void scan0_wsplit(const float* __restrict__ inputs,
                             uint32_t* __restrict__ s0,
                             const float* __restrict__ W1,
                             const float* __restrict__ W2,
                             ushort_t* __restrict__ w1h, ushort_t* __restrict__ w1l,
                             ushort_t* __restrict__ w2h, ushort_t* __restrict__ w2l) {
    const int bid = blockIdx.x;
    if (bid < (BB * N0) / 64) {
        scan_body<N0, 0>(inputs, s0, nullptr, bid * 64 + threadIdx.x);
    } else {
        int i = (bid - (BB * N0) / 64) * 64 + threadIdx.x;  // 0..524287
        float a = 20.0f * W1[i];
        ushort_t h = f2b(a);
        w1h[i] = h; w1l[i] = f2b(a - b2f(h));
        float b = 20.0f * W2[i];
        h = f2b(b);
        w2h[i] = h; w2l[i] = f2b(b - b2f(h));
    }
}

template <int NW>
__global__ void scan_mid(const float* __restrict__ drive,
                         uint32_t* __restrict__ sout) {
    scan_body<NW, 1>(drive, sout, nullptr,
                     blockIdx.x * blockDim.x + threadIdx.x);
}

__global__ void scan_last(const float* __restrict__ drive,
                          float* __restrict__ out) {
    scan_body<N2, 2>(drive, nullptr, out,
                     blockIdx.x * blockDim.x + threadIdx.x);
}

// ---------------- bf16x3-split MFMA GEMM, packed A, 1-barrier dbuf ---------
// C[M,N] = A[M,K]*B[N,K]^T; A packed (hi|lo<<16) unpacked via v_perm during
// staging; B pre-split planes via global_load_lds (waves 2,3).
// 128x128 tile, BK=32, double-buffered LDS, one barrier per K-tile:
// loads for tile ks+1 are issued BEFORE the MFMAs of tile ks, written after.
template <int NBY>
__global__ __launch_bounds__(256, 2) void gemm_x3(
    const uint32_t* __restrict__ Apk,
    const ushort_t* __restrict__ Bh, const ushort_t* __restrict__ Bl,
    float* __restrict__ C, int Ncols, int K) {
    __shared__ char lds[65536];  // 2 bufs x {Ah|Al|Bh|Bl, 8KB each}
    const int tid = threadIdx.x;
    const int lane = tid & 63, wave = tid >> 6;

    // bijective XCD swizzle (m204)
    const int id = blockIdx.x, nwg = gridDim.x;
    const int qq = nwg >> 3, rr = nwg & 7;
    const int xcd = id & 7, jj = id >> 3;
    const int wg = (xcd < rr ? xcd * (qq + 1) : rr * (qq + 1) + (xcd - rr) * qq) + jj;
    const int m0 = (wg / NBY) * 128;
    const int n0 = (wg % NBY) * 128;

    // B staging (waves 2,3): pre-swizzled global source, linear LDS dest
    const ushort_t* gB = (wave == 2) ? Bh : Bl;
    const int chunk_sw = (lane & 3) ^ ((lane >> 3) & 3);
    const size_t rowbB = (size_t)K * 2;
    const char* gsrcB = (const char*)gB +
                        (size_t)(n0 + (lane >> 2)) * rowbB + (size_t)chunk_sw * 16;

    // A staging (all 256 threads): 4 x uint4 (16 packed elems) per K-tile
    const int r0 = tid >> 3, c4 = tid & 7;
    const int ch = (c4 >> 1) ^ ((r0 >> 1) & 3);     // swizzled 16B slot
    const int aoff = r0 * 64 + ch * 16 + (c4 & 1) * 8;
    const uint32_t* aSrc = Apk + (size_t)(m0 + r0) * K + c4 * 4;

    const int KSTEPS = K / 32;  // 16 or 32 (always even)

    f32x4 acc[4][4];
#pragma unroll
    for (int i = 0; i < 4; ++i)
#pragma unroll
        for (int j = 0; j < 4; ++j) acc[i][j] = (f32x4){0.f, 0.f, 0.f, 0.f};

    const int wm = wave >> 1, wn = wave & 1;
    const int r4 = lane & 15, kg = lane >> 4;
    const int slot = kg ^ ((r4 >> 1) & 3);
    const int fA = (wm * 64 + r4) * 64 + slot * 16;
    const int fB = (wn * 64 + r4) * 64 + slot * 16;

    auto issueB = [&](int ks, int base) {
#pragma unroll
        for (int i = 0; i < 8; ++i) {
            __builtin_amdgcn_global_load_lds(
                (const __attribute__((address_space(1))) uint32_t*)(
                    gsrcB + (size_t)i * 16 * rowbB + (size_t)ks * 64),
                (__attribute__((address_space(3))) uint32_t*)(
                    lds + base + 16384 + (wave - 2) * 8192 + i * 1024),
                16, 0, 0);
        }
    };
    auto loadA = [&](int ks, uint4* pk) {
#pragma unroll
        for (int i = 0; i < 4; ++i)
            pk[i] = *reinterpret_cast<const uint4*>(
                aSrc + (size_t)i * 32 * K + (size_t)ks * 32);
    };
    auto writeA = [&](const uint4* pk, int base) {
#pragma unroll
        for (int i = 0; i < 4; ++i) {
            uint32_t hi01 = __builtin_amdgcn_perm(pk[i].y, pk[i].x, 0x05040100u);
            uint32_t lo01 = __builtin_amdgcn_perm(pk[i].y, pk[i].x, 0x07060302u);
            uint32_t hi23 = __builtin_amdgcn_perm(pk[i].w, pk[i].z, 0x05040100u);
            uint32_t lo23 = __builtin_amdgcn_perm(pk[i].w, pk[i].z, 0x07060302u);
            *reinterpret_cast<uint2*>(lds + base + aoff + i * 2048) =
                make_uint2(hi01, hi23);
            *reinterpret_cast<uint2*>(lds + base + 8192 + aoff + i * 2048) =
                make_uint2(lo01, lo23);
        }
    };
    auto compute = [&](int base) {
        short8 ah[4], al[4], bh[4], bl[4];
#pragma unroll
        for (int i = 0; i < 4; ++i) {
            ah[i] = *(const short8*)(lds + base + 0     + fA + i * 1024);
            al[i] = *(const short8*)(lds + base + 8192  + fA + i * 1024);
            bh[i] = *(const short8*)(lds + base + 16384 + fB + i * 1024);
            bl[i] = *(const short8*)(lds + base + 24576 + fB + i * 1024);
        }
#pragma unroll
        for (int i = 0; i < 4; ++i)
#pragma unroll
            for (int j = 0; j < 4; ++j) {
                acc[i][j] = __builtin_amdgcn_mfma_f32_16x16x32_bf16(
                    ah[i], bh[j], acc[i][j], 0, 0, 0);
                acc[i][j] = __builtin_amdgcn_mfma_f32_16x16x32_bf16(
                    ah[i], bl[j], acc[i][j], 0, 0, 0);
                acc[i][j] = __builtin_amdgcn_mfma_f32_16x16x32_bf16(
                    al[i], bh[j], acc[i][j], 0, 0, 0);
            }
    };

    // prologue: tile 0 -> buf0
    {
        if (wave >= 2) issueB(0, 0);
        uint4 pk[4];
        loadA(0, pk);
        writeA(pk, 0);
        __syncthreads();
    }

    for (int ks = 0; ks < KSTEPS; ks += 2) {
        {   // read buf0 (tile ks), stage tile ks+1 -> buf1
            if (wave >= 2) issueB(ks + 1, 32768);
            uint4 pk[4];
            loadA(ks + 1, pk);
            compute(0);
            writeA(pk, 32768);
            __syncthreads();
        }
        {   // read buf1 (tile ks+1), stage tile ks+2 -> buf0 (if any)
            const bool more = (ks + 2 < KSTEPS);
            uint4 pk[4];
            if (wave >= 2 && more) issueB(ks + 2, 0);
            if (more) loadA(ks + 2, pk);
            compute(32768);
            if (more) writeA(pk, 0);
            __syncthreads();
        }
    }

    // epilogue: C/D layout col=lane&15, row=(lane>>4)*4+reg
#pragma unroll
    for (int i = 0; i < 4; ++i)
#pragma unroll
        for (int j = 0; j < 4; ++j)
#pragma unroll
            for (int r = 0; r < 4; ++r) {
                int row = m0 + wm * 64 + i * 16 + kg * 4 + r;
                int col = n0 + wn * 64 + j * 16 + r4;
                C[(size_t)row * Ncols + col] = acc[i][j][r];
            }
}

extern "C" void kernel_launch(void* const* d_in, const int* in_sizes, int n_in,
                              void* d_out, int out_size, void* d_ws,
                              size_t ws_size, hipStream_t stream) {
    const float* inputs = (const float*)d_in[0];  // [500,32,512]
    const float* W1 = (const float*)d_in[1];      // [1024,512]
    const float* W2 = (const float*)d_in[2];      // [512,1024]
    float* out = (float*)d_out;                   // [500,32,512]
    char* ws = (char*)d_ws;

    // workspace (bytes):
    //  region A [0, 65,536,000): s0 packed u32 (32.77MB); later s1 packed (65.54MB)
    //  region B [65,536,000, 131,072,000): x1 f32 (65.54MB); later x2 f32
    //  weights  [131,072,000, 135,266,304): w1h w1l w2h w2l (1MB each)
    uint32_t* s0 = (uint32_t*)ws;
    uint32_t* s1 = (uint32_t*)ws;             // s0 dead after gemm1
    float*    x1 = (float*)(ws + 65536000);
    float*    x2 = (float*)(ws + 65536000);   // x1 dead after scan1
    ushort_t* w1h = (ushort_t*)(ws + 131072000);
    ushort_t* w1l = (ushort_t*)(ws + 132120576);
    ushort_t* w2h = (ushort_t*)(ws + 133169152);
    ushort_t* w2l = (ushort_t*)(ws + 134217728);

    // 1) layer-0 recurrence -> packed sigma, fused with weight split
    scan0_wsplit<<<256 + 8192, 64, 0, stream>>>(inputs, s0, W1, W2,
                                                w1h, w1l, w2h, w2l);
    // 2) X1 = S0 @ (20*W1)^T -> f32 [16000,1024]
    gemm_x3<8><<<1000, 256, 0, stream>>>(s0, w1h, w1l, x1, N1, N0);
    // 3) layer-1 recurrence -> packed sigma
    scan_mid<N1><<<512, 64, 0, stream>>>(x1, s1);
    // 4) X2 = S1 @ (20*W2)^T -> f32 [16000,512]
    gemm_x3<4><<<500, 256, 0, stream>>>(s1, w2h, w2l, x2, N2, N1);
    // 5) layer-2 recurrence -> spikes (20*sigma) -> out
    scan_last<<<256, 64, 0, stream>>>(x2, out);
}